// Round 2
// baseline (382.264 us; speedup 1.0000x reference)
//
#include <hip/hip_runtime.h>
#include <hip/hip_bf16.h>

// KL(N(mu_p, diag(exp(ls_p))) || N(mu_q, diag(exp(ls_q)))) -> scalar:
//   out = 0.5 * ( S / N_samples - d )
//   S = sum over all elements of
//       (ls_q - ls_p) + exp(ls_p - ls_q) + (m_q - m_p)^2 * exp(-ls_q)
// Shapes: (2,3,160,192,160) fp32, N_total = 29,491,200 = 7200*256*16.
//
// R1 lesson: grid-stride loop compiled to VGPR_Count=16 -> the 4 float4
// loads shared one register destination with waitcnt between them -> ~1
// load in flight -> 3.3 TB/s effective. Fix: exact-fit grid, each thread
// loads 4 float4 per array (16 independent 16B loads issued before any
// use), forcing the compiler to keep them all in flight.

#define THREADS 256
#define UNROLL  4

__global__ __launch_bounds__(THREADS) void kl_reduce_kernel(
    const float4* __restrict__ mp, const float4* __restrict__ lsp,
    const float4* __restrict__ mq, const float4* __restrict__ lsq,
    double* __restrict__ partials, long n4, long T)
{
    long base = (long)blockIdx.x * THREADS + threadIdx.x;

    float4 A[UNROLL], B[UNROLL], C[UNROLL], D[UNROLL];
    bool valid[UNROLL];

    // Issue all 16 loads before any consumption (independent dests).
    #pragma unroll
    for (int k = 0; k < UNROLL; ++k) {
        long idx = base + (long)k * T;
        valid[k] = idx < n4;
        long i = valid[k] ? idx : 0;
        A[k] = mp[i];
        B[k] = lsp[i];
        C[k] = mq[i];
        D[k] = lsq[i];
    }

    double acc = 0.0;
    #pragma unroll
    for (int k = 0; k < UNROLL; ++k) {
        float4 a = A[k], b = B[k], c = C[k], d = D[k];
        float dx = c.x - a.x, dy = c.y - a.y, dz = c.z - a.z, dw = c.w - a.w;
        float eqx = __expf(-d.x), eqy = __expf(-d.y), eqz = __expf(-d.z), eqw = __expf(-d.w);
        float epx = __expf(b.x), epy = __expf(b.y), epz = __expf(b.z), epw = __expf(b.w);
        float e0 = (d.x - b.x) + epx * eqx + dx * dx * eqx;
        float e1 = (d.y - b.y) + epy * eqy + dy * dy * eqy;
        float e2 = (d.z - b.z) + epz * eqz + dz * dz * eqz;
        float e3 = (d.w - b.w) + epw * eqw + dw * dw * eqw;
        float s = (e0 + e1) + (e2 + e3);
        acc += valid[k] ? (double)s : 0.0;
    }

    // wave (64-lane) reduction
    #pragma unroll
    for (int off = 32; off > 0; off >>= 1)
        acc += __shfl_down(acc, off, 64);

    __shared__ double sdata[THREADS / 64];
    int wave = threadIdx.x >> 6;
    if ((threadIdx.x & 63) == 0) sdata[wave] = acc;
    __syncthreads();

    if (threadIdx.x == 0) {
        double s = 0.0;
        #pragma unroll
        for (int w = 0; w < THREADS / 64; ++w) s += sdata[w];
        partials[blockIdx.x] = s;
    }
}

__global__ __launch_bounds__(256) void kl_finalize_kernel(
    const double* __restrict__ partials, int nblocks,
    float* __restrict__ out, double inv_nsamp, double dch)
{
    double acc = 0.0;
    for (int i = threadIdx.x; i < nblocks; i += blockDim.x)
        acc += partials[i];

    #pragma unroll
    for (int off = 32; off > 0; off >>= 1)
        acc += __shfl_down(acc, off, 64);

    __shared__ double sdata[4];
    int wave = threadIdx.x >> 6;
    if ((threadIdx.x & 63) == 0) sdata[wave] = acc;
    __syncthreads();

    if (threadIdx.x == 0) {
        double s = 0.0;
        #pragma unroll
        for (int w = 0; w < 4; ++w) s += sdata[w];
        out[0] = (float)(0.5 * (s * inv_nsamp - dch));
    }
}

extern "C" void kernel_launch(void* const* d_in, const int* in_sizes, int n_in,
                              void* d_out, int out_size, void* d_ws, size_t ws_size,
                              hipStream_t stream) {
    const float4* mp  = (const float4*)d_in[0];
    const float4* lsp = (const float4*)d_in[1];
    const float4* mq  = (const float4*)d_in[2];
    const float4* lsq = (const float4*)d_in[3];

    long n_total = (long)in_sizes[0];        // 29,491,200
    long n4 = n_total / 4;                   // 7,372,800 (exact)
    const long d_ch = 3;
    double n_samples = (double)(n_total / d_ch);

    // Each thread handles UNROLL float4s; exact fit: 7200 blocks.
    long blocks = (n4 + (long)THREADS * UNROLL - 1) / ((long)THREADS * UNROLL);
    long T = blocks * THREADS;               // stride between unroll chunks

    double* partials = (double*)d_ws;        // blocks * 8 B = 57.6 KB

    kl_reduce_kernel<<<(int)blocks, THREADS, 0, stream>>>(mp, lsp, mq, lsq,
                                                          partials, n4, T);
    kl_finalize_kernel<<<1, 256, 0, stream>>>(partials, (int)blocks, (float*)d_out,
                                              1.0 / n_samples, (double)d_ch);
}